// Round 1
// baseline (148.214 us; speedup 1.0000x reference)
//
#include <hip/hip_runtime.h>
#include <math.h>

// TripletLoss round 6: class-sorted rows + LDS-free dist kernel.
//
// Pipeline: memset -> hist -> scan -> prep(scatter by class) -> dist -> combine -> final.
//
// dist: Xbf (2 MB, L2-resident) is read straight into MFMA fragments with
// global_load_dwordx4 (no LDS staging, no barriers in the K-loop). Rows are
// permuted so each 64-col strip's same-class rows lie in a contiguous window
// [U0,U1); tiles outside the window take a 3-op epilogue (Sa += a, v=ur-a,
// Mn=min) -- ~96% of tiles. Tiles inside take the full tag-check path
// (Ss/Mp/self-exclusion), identical numerics to round 5.

#define NROWS 8192
#define MARGIN_F 0.3f

typedef short bf16x8 __attribute__((ext_vector_type(8)));
typedef float f32x16 __attribute__((ext_vector_type(16)));
union U4B { uint4 u; bf16x8 h; };

__device__ __forceinline__ unsigned short f2bf(float x) {
    unsigned u = __float_as_uint(x);
    return (unsigned short)((u + 0x7fffu + ((u >> 16) & 1u)) >> 16);
}

// ---- K0a: class histogram ----
__global__ __launch_bounds__(256) void hist_kernel(const int* __restrict__ tgt,
                                                   int* __restrict__ hist) {
    int i = blockIdx.x * 256 + threadIdx.x;
    atomicAdd(&hist[tgt[i]], 1);
}

// ---- K0b: exclusive prefix scan over 256 class counts ----
__global__ __launch_bounds__(256) void scan_kernel(const int* __restrict__ hist,
                                                   int* __restrict__ cstart,
                                                   int* __restrict__ coffset) {
    int t = threadIdx.x;
    int h = hist[t];
    int x = h;
    #pragma unroll
    for (int d = 1; d < 64; d <<= 1) {
        int y = __shfl_up(x, d, 64);
        if ((t & 63) >= d) x += y;
    }
    __shared__ int wsum[4];
    if ((t & 63) == 63) wsum[t >> 6] = x;
    __syncthreads();
    int off = 0;
    for (int i = 0; i < (t >> 6); ++i) off += wsum[i];
    int excl = off + x - h;              // exclusive prefix
    cstart[t] = excl;
    coffset[t] = excl;
    if (t == 255) cstart[256] = NROWS;
}

// ---- K1: bf16 convert + scatter rows into class-sorted order ----
__global__ __launch_bounds__(256) void prep_kernel(const float* __restrict__ X,
                                                   const int* __restrict__ tgt,
                                                   float* __restrict__ sq,
                                                   float* __restrict__ upk,
                                                   unsigned short* __restrict__ Xbf,
                                                   int* __restrict__ coffset,
                                                   float* __restrict__ S_class,
                                                   float* __restrict__ bsum) {
    int tid = threadIdx.x, w = tid >> 6, l = tid & 63;
    int row0 = blockIdx.x * 32 + w * 8;
    float rs = 0.0f;
    #pragma unroll
    for (int i = 0; i < 8; ++i) {
        int r = row0 + i;
        float2 v = ((const float2*)X)[(size_t)r * 64 + l];
        ushort2 h2;
        h2.x = f2bf(v.x);
        h2.y = f2bf(v.y);
        float s = v.x * v.x + v.y * v.y;
        for (int d = 32; d > 0; d >>= 1) s += __shfl_down(s, d, 64);
        int pos = 0;
        if (l == 0) {
            int c = tgt[r];
            pos = atomicAdd(&coffset[c], 1);
            sq[pos] = s;
            rs += s;
            upk[pos] = __uint_as_float((__float_as_uint(0.5f * s) & 0xffffff00u) | (unsigned)c);
            atomicAdd(&S_class[c], s);
        }
        pos = __shfl(pos, 0, 64);
        ((ushort2*)Xbf)[(size_t)pos * 64 + l] = h2;
    }
    __shared__ float bs[4];
    if (l == 0) bs[w] = rs;
    __syncthreads();
    if (tid == 0) bsum[blockIdx.x] = bs[0] + bs[1] + bs[2] + bs[3];
}

// ---- K2: MFMA Gram + fused column stats, operands straight from L2 ----
__global__ __launch_bounds__(256, 3) void dist_kernel(
        const unsigned short* __restrict__ Xbf, const float* __restrict__ upk,
        const int* __restrict__ cstart, float4* __restrict__ partial,
        int ns_mask, int jb_shift, int tiles) {
    const int tid = threadIdx.x;
    const int w = tid >> 6, l = tid & 63, hl = l >> 5, l31 = l & 31;
    const int bx = blockIdx.x;
    const int slice = bx & ns_mask;   // bx%8 = XCD id -> XCD k hosts slices {k,k+8}
    const int jb = bx >> jb_shift;    // 64-col strip
    const int col0 = jb * 64;

    // B fragments direct from global (row-major bf16 rows, L2-hot).
    bf16x8 Bf[2][8];
    int tjt[2];
    #pragma unroll
    for (int ct = 0; ct < 2; ++ct) {
        int colb = col0 + ct * 32 + l31;
        tjt[ct] = __float_as_int(upk[colb]) & 0xff;
        const uint4* brow = (const uint4*)Xbf + (size_t)colb * 16;
        #pragma unroll
        for (int kk = 0; kk < 8; ++kk) {
            U4B t; t.u = brow[kk * 2 + hl];
            Bf[ct][kk] = t.h;
        }
    }
    // same-class row window for the whole strip (classes ascending with row)
    const int c_first = __float_as_int(upk[col0]) & 0xff;
    const int c_last  = __float_as_int(upk[col0 + 63]) & 0xff;
    const int U0 = cstart[c_first];
    const int U1 = cstart[c_last + 1];

    float Sa[2] = {0.f, 0.f};
    float Ss[2] = {0.f, 0.f};
    float Mp[2] = {-INFINITY, -INFINITY};
    float Mn[2] = { INFINITY,  INFINITY};

    for (int t = 0; t < tiles; ++t) {
        const int i0 = (slice * tiles + t) * 128;
        const uint4* ap = (const uint4*)Xbf + (size_t)(i0 + w * 32 + l31) * 16;
        const float4* up = (const float4*)(upk + i0 + w * 32 + 4 * hl);

        float ur[16];
        #pragma unroll
        for (int g = 0; g < 4; ++g) {
            float4 u4 = up[g * 2];
            ur[g * 4 + 0] = u4.x; ur[g * 4 + 1] = u4.y;
            ur[g * 4 + 2] = u4.z; ur[g * 4 + 3] = u4.w;
        }

        f32x16 acc[2];
        acc[0] = (f32x16)0.0f;
        acc[1] = (f32x16)0.0f;
        #pragma unroll
        for (int kk = 0; kk < 8; ++kk) {
            U4B a; a.u = ap[kk * 2 + hl];
            acc[0] = __builtin_amdgcn_mfma_f32_32x32x16_bf16(a.h, Bf[0][kk], acc[0], 0, 0, 0);
            acc[1] = __builtin_amdgcn_mfma_f32_32x32x16_bf16(a.h, Bf[1][kk], acc[1], 0, 0, 0);
        }

        if (i0 < U1 && i0 + 128 > U0) {
            // slow tile: contains same-class rows for some column of the strip
            #pragma unroll
            for (int ct = 0; ct < 2; ++ct) {
                const int tt = tjt[ct];
                #pragma unroll
                for (int r = 0; r < 16; ++r) {
                    float a = acc[ct][r];
                    float v = ur[r] - a;
                    bool same = ((__float_as_int(ur[r]) & 0xff) == tt);
                    Sa[ct] += a;
                    Ss[ct] += same ? a : 0.0f;
                    Mp[ct] = fmaxf(Mp[ct], same ? v : -INFINITY);
                    Mn[ct] = same ? Mn[ct] : fminf(Mn[ct], v);
                }
            }
        } else {
            // fast tile: pure negatives -- 3 VALU ops per element
            #pragma unroll
            for (int ct = 0; ct < 2; ++ct) {
                #pragma unroll
                for (int r = 0; r < 16; ++r) {
                    float a = acc[ct][r];
                    Sa[ct] += a;
                    Mn[ct] = fminf(Mn[ct], ur[r] - a);
                }
            }
        }
    }

    // merge half-lanes, then 4 waves via small LDS, write coalesced partial
    #pragma unroll
    for (int ct = 0; ct < 2; ++ct) {
        Sa[ct] += __shfl_xor(Sa[ct], 32, 64);
        Ss[ct] += __shfl_xor(Ss[ct], 32, 64);
        Mp[ct] = fmaxf(Mp[ct], __shfl_xor(Mp[ct], 32, 64));
        Mn[ct] = fminf(Mn[ct], __shfl_xor(Mn[ct], 32, 64));
    }
    __shared__ float4 sm[64 * 4];
    if (l < 32) {
        #pragma unroll
        for (int ct = 0; ct < 2; ++ct)
            sm[(ct * 32 + l31) * 4 + w] = make_float4(Sa[ct], Ss[ct], Mp[ct], Mn[ct]);
    }
    __syncthreads();
    if (tid < 64) {
        float4 a = sm[tid * 4 + 0], b = sm[tid * 4 + 1];
        float4 c2 = sm[tid * 4 + 2], d = sm[tid * 4 + 3];
        float4 o;
        o.x = a.x + b.x + c2.x + d.x;
        o.y = a.y + b.y + c2.y + d.y;
        o.z = fmaxf(fmaxf(a.z, b.z), fmaxf(c2.z, d.z));
        o.w = fminf(fminf(a.w, b.w), fminf(c2.w, d.w));
        partial[(size_t)slice * NROWS + col0 + tid] = o;
    }
}

// ---- K3: per-row loss (thread per permuted row), block sums ----
__global__ __launch_bounds__(256) void combine_kernel(
        const float* __restrict__ sq, const float* __restrict__ upk,
        const int* __restrict__ hist, const float* __restrict__ S_class,
        const float* __restrict__ bsum, const float4* __restrict__ partial,
        float* __restrict__ blocksum, int ns) {
    __shared__ float red[4];
    __shared__ float hs[4];
    int tid = threadIdx.x, l = tid & 63, w = tid >> 6;

    // S_all = sum of prep's 256 per-block sums
    float b = bsum[tid];
    for (int d = 32; d > 0; d >>= 1) b += __shfl_down(b, d, 64);
    if (l == 0) red[w] = b;
    __syncthreads();
    float S_all = red[0] + red[1] + red[2] + red[3];

    int j = blockIdx.x * 256 + tid;
    float Sa = 0.f, Ss = 0.f, Mp = -INFINITY, Mn = INFINITY;
    for (int s = 0; s < ns; ++s) {
        float4 p = partial[(size_t)s * NROWS + j];
        Sa += p.x; Ss += p.y;
        Mp = fmaxf(Mp, p.z); Mn = fminf(Mn, p.w);
    }
    float sqj = sq[j];
    int c = __float_as_int(upk[j]) & 0xff;
    float cnt = (float)hist[c];
    float sumall = (float)NROWS * sqj + S_all - 2.0f * Sa;
    float sump = cnt * sqj + S_class[c] - 2.0f * Ss;
    float sumn = sumall - sump;
    float sigp = sump / (cnt - 1.0f);
    float sign_ = sumn / ((float)NROWS - cnt);
    float ap = (sqj + 2.0f * Mp) / sigp + 0.5f * __logf(sigp);
    float an = (sqj + 2.0f * Mn) / sign_ + 0.5f * __logf(sign_);
    float h = fmaxf(ap - an + MARGIN_F, 0.0f);
    for (int d = 32; d > 0; d >>= 1) h += __shfl_down(h, d, 64);
    if (l == 0) hs[w] = h;
    __syncthreads();
    if (tid == 0) blocksum[blockIdx.x] = hs[0] + hs[1] + hs[2] + hs[3];
}

// ---- K4: final mean ----
__global__ __launch_bounds__(64) void final_kernel(const float* __restrict__ blocksum,
                                                   float* __restrict__ out) {
    int tid = threadIdx.x;
    float s = (tid < 32) ? blocksum[tid] : 0.0f;
    for (int d = 32; d > 0; d >>= 1) s += __shfl_down(s, d, 64);
    if (tid == 0) out[0] = s * (1.0f / NROWS);
}

extern "C" void kernel_launch(void* const* d_in, const int* in_sizes, int n_in,
                              void* d_out, int out_size, void* d_ws, size_t ws_size,
                              hipStream_t stream) {
    const float* X = (const float*)d_in[0];
    const int* tgt = (const int*)d_in[1];
    float* out = (float*)d_out;

    float* f = (float*)d_ws;
    int*   hist     = (int*)f;                 // [0,256)      memset 0
    float* S_class  = f + 256;                 // [256,512)    memset 0
    float* bsum     = f + 512;                 // [512,768)
    float* blocksum = f + 768;                 // [768,800)
    int*   cstart   = (int*)(f + 800);         // [800,1057)
    int*   coffset  = (int*)(f + 1088);        // [1088,1344)
    float* sq       = f + 2048;                // [2048,10240)
    float* upk      = f + 10240;               // [10240,18432)
    unsigned short* Xbf = (unsigned short*)(f + 18432);  // bf16[1M] -> [18432,542720)
    float4* partial = (float4*)(f + 542720);   // ns*8192 float4

    int ns = 16;
    while (ns > 2 && ws_size < ((size_t)542720 + (size_t)ns * NROWS * 4) * sizeof(float))
        ns >>= 1;
    int shift = (ns == 16) ? 4 : (ns == 8) ? 3 : 2;
    int tiles = 64 / ns;

    hipMemsetAsync(d_ws, 0, 2048, stream);     // hist + S_class
    hist_kernel<<<32, 256, 0, stream>>>(tgt, hist);
    scan_kernel<<<1, 256, 0, stream>>>(hist, cstart, coffset);
    prep_kernel<<<256, 256, 0, stream>>>(X, tgt, sq, upk, Xbf, coffset, S_class, bsum);
    dist_kernel<<<128 * ns, 256, 0, stream>>>(Xbf, upk, cstart, partial,
                                              ns - 1, shift, tiles);
    combine_kernel<<<32, 256, 0, stream>>>(sq, upk, hist, S_class, bsum,
                                           partial, blocksum, ns);
    final_kernel<<<1, 64, 0, stream>>>(blocksum, out);
}

// Round 2
// 138.006 us; speedup vs baseline: 1.0740x; 1.0740x over previous
//
#include <hip/hip_runtime.h>
#include <math.h>

// TripletLoss round 7: class-sorted rows + pipelined global_load_lds staging
// + fused launches (4 dispatches total).
//
// Pipeline: histscan(1 blk, zeros S_class/done, builds cstart/coffset)
//           -> prep (scatter rows by class, bf16 convert)
//           -> dist (MFMA Gram + fused column stats)
//           -> combine (per-row loss + last-block final reduction).
//
// dist staging: LDS dest is linear (global_load_lds requirement); the XOR
// swizzle lives in the *source* address: slot L holds src[(L&~15)|((L&15)^((L>>4)&15))],
// so ds_read As[row*16 + ((kk*2+hl)^(row&15))] returns src[row*16 + kk*2+hl].
// K-loop schedule (single buffer): read frags(t) -> barrier -> issue stage(t+1)
// async + ur loads -> MFMA+epilogue (hides stage latency) -> barrier.
// ~96% of tiles are pure-negative (sorted classes): 3-op epilogue.

#define NROWS 8192
#define MARGIN_F 0.3f

typedef short bf16x8 __attribute__((ext_vector_type(8)));
typedef float f32x16 __attribute__((ext_vector_type(16)));
union U4B { uint4 u; bf16x8 h; };

__device__ __forceinline__ unsigned short f2bf(float x) {
    unsigned u = __float_as_uint(x);
    return (unsigned short)((u + 0x7fffu + ((u >> 16) & 1u)) >> 16);
}

// ---- K0: fused histogram + exclusive scan + zero-init (single block) ----
__global__ __launch_bounds__(256) void histscan_kernel(const int* __restrict__ tgt,
                                                       int* __restrict__ hist,
                                                       int* __restrict__ cstart,
                                                       int* __restrict__ coffset,
                                                       float* __restrict__ S_class,
                                                       int* __restrict__ done) {
    __shared__ int h[256];
    __shared__ int wsum[4];
    int t = threadIdx.x;
    h[t] = 0;
    S_class[t] = 0.0f;          // zero for prep's atomics (replaces memset)
    if (t == 0) *done = 0;      // combine's last-block counter
    __syncthreads();
    for (int i = t; i < NROWS; i += 256) atomicAdd(&h[tgt[i]], 1);
    __syncthreads();
    int hv = h[t];
    hist[t] = hv;
    int x = hv;
    #pragma unroll
    for (int d = 1; d < 64; d <<= 1) {
        int y = __shfl_up(x, d, 64);
        if ((t & 63) >= d) x += y;
    }
    if ((t & 63) == 63) wsum[t >> 6] = x;
    __syncthreads();
    int off = 0;
    for (int i = 0; i < (t >> 6); ++i) off += wsum[i];
    int excl = off + x - hv;    // exclusive prefix
    cstart[t] = excl;
    coffset[t] = excl;
    if (t == 255) cstart[256] = NROWS;
}

// ---- K1: bf16 convert + scatter rows into class-sorted order ----
__global__ __launch_bounds__(256) void prep_kernel(const float* __restrict__ X,
                                                   const int* __restrict__ tgt,
                                                   float* __restrict__ sq,
                                                   float* __restrict__ upk,
                                                   unsigned short* __restrict__ Xbf,
                                                   int* __restrict__ coffset,
                                                   float* __restrict__ S_class,
                                                   float* __restrict__ bsum) {
    int tid = threadIdx.x, w = tid >> 6, l = tid & 63;
    int row0 = blockIdx.x * 32 + w * 8;
    float rs = 0.0f;
    #pragma unroll
    for (int i = 0; i < 8; ++i) {
        int r = row0 + i;
        float2 v = ((const float2*)X)[(size_t)r * 64 + l];
        ushort2 h2;
        h2.x = f2bf(v.x);
        h2.y = f2bf(v.y);
        float s = v.x * v.x + v.y * v.y;
        for (int d = 32; d > 0; d >>= 1) s += __shfl_down(s, d, 64);
        int pos = 0;
        if (l == 0) {
            int c = tgt[r];
            pos = atomicAdd(&coffset[c], 1);
            sq[pos] = s;
            rs += s;
            upk[pos] = __uint_as_float((__float_as_uint(0.5f * s) & 0xffffff00u) | (unsigned)c);
            atomicAdd(&S_class[c], s);
        }
        pos = __shfl(pos, 0, 64);
        ((ushort2*)Xbf)[(size_t)pos * 64 + l] = h2;
    }
    __shared__ float bs[4];
    if (l == 0) bs[w] = rs;
    __syncthreads();
    if (tid == 0) bsum[blockIdx.x] = bs[0] + bs[1] + bs[2] + bs[3];
}

// ---- K2: MFMA Gram + fused column stats, pipelined async LDS staging ----
__global__ __launch_bounds__(256, 3) void dist_kernel(
        const unsigned short* __restrict__ Xbf, const float* __restrict__ upk,
        const int* __restrict__ cstart, float4* __restrict__ partial,
        int ns_mask, int jb_shift, int tiles) {
    __shared__ uint4 As[128 * 16];
    __shared__ float4 sm[64 * 4];
    const int tid = threadIdx.x;
    const int w = tid >> 6, l = tid & 63, hl = l >> 5, l31 = l & 31;
    const int bx = blockIdx.x;
    const int slice = bx & ns_mask;   // bx%8 = XCD id -> XCD k hosts slices {k,k+8}
    const int jb = bx >> jb_shift;    // 64-col strip
    const int col0 = jb * 64;

    // ---- stage B strip (64 rows = 16 KB), swizzled-source async copy ----
    {
        const uint4* srcb = (const uint4*)Xbf + (size_t)col0 * 16;
        #pragma unroll
        for (int s = 0; s < 4; ++s) {
            int L = s * 256 + w * 64 + l;
            int si = (L & ~15) | ((L & 15) ^ ((L >> 4) & 15));
            __builtin_amdgcn_global_load_lds(
                (const __attribute__((address_space(1))) unsigned int*)(srcb + si),
                (__attribute__((address_space(3))) unsigned int*)(As + s * 256 + w * 64),
                16, 0, 0);
        }
    }
    // same-class row window for the whole strip (classes ascending with row)
    const int c_first = __float_as_int(upk[col0]) & 0xff;
    const int c_last  = __float_as_int(upk[col0 + 63]) & 0xff;
    const int U0 = cstart[c_first];
    const int U1 = cstart[c_last + 1];
    __syncthreads();

    bf16x8 Bf[2][8];
    int tjt[2];
    #pragma unroll
    for (int ct = 0; ct < 2; ++ct) {
        int colb = ct * 32 + l31;
        tjt[ct] = __float_as_int(upk[col0 + colb]) & 0xff;
        #pragma unroll
        for (int kk = 0; kk < 8; ++kk) {
            U4B tb; tb.u = As[colb * 16 + ((kk * 2 + hl) ^ (colb & 15))];
            Bf[ct][kk] = tb.h;
        }
    }
    __syncthreads();   // everyone done reading B region of As

    // ---- stage A tile 0 ----
    {
        const uint4* srca = (const uint4*)Xbf + (size_t)(slice * tiles) * 128 * 16;
        #pragma unroll
        for (int s = 0; s < 8; ++s) {
            int L = s * 256 + w * 64 + l;
            int si = (L & ~15) | ((L & 15) ^ ((L >> 4) & 15));
            __builtin_amdgcn_global_load_lds(
                (const __attribute__((address_space(1))) unsigned int*)(srca + si),
                (__attribute__((address_space(3))) unsigned int*)(As + s * 256 + w * 64),
                16, 0, 0);
        }
    }
    __syncthreads();   // tile 0 landed (vmcnt drained by barrier)

    float Sa[2] = {0.f, 0.f};
    float Ss[2] = {0.f, 0.f};
    float Mp[2] = {-INFINITY, -INFINITY};
    float Mn[2] = { INFINITY,  INFINITY};
    const int arow = w * 32 + l31;

    for (int t = 0; t < tiles; ++t) {
        const int i0 = (slice * tiles + t) * 128;

        // [A] pull this tile's A fragments into registers
        uint4 af[8];
        #pragma unroll
        for (int kk = 0; kk < 8; ++kk)
            af[kk] = As[arow * 16 + ((kk * 2 + hl) ^ (arow & 15))];
        __syncthreads();   // B1: frag reads done everywhere -> As reusable

        // [C1] ur loads (issued before stage so their wait is vmcnt(8), not 0)
        float ur[16];
        const float4* up = (const float4*)(upk + i0 + w * 32 + 4 * hl);
        #pragma unroll
        for (int g = 0; g < 4; ++g) {
            float4 u4 = up[g * 2];
            ur[g * 4 + 0] = u4.x; ur[g * 4 + 1] = u4.y;
            ur[g * 4 + 2] = u4.z; ur[g * 4 + 3] = u4.w;
        }
        // [C2] issue next tile's async stage; lands during MFMA+epilogue
        if (t + 1 < tiles) {
            const uint4* srca = (const uint4*)Xbf + (size_t)(i0 + 128) * 16;
            #pragma unroll
            for (int s = 0; s < 8; ++s) {
                int L = s * 256 + w * 64 + l;
                int si = (L & ~15) | ((L & 15) ^ ((L >> 4) & 15));
                __builtin_amdgcn_global_load_lds(
                    (const __attribute__((address_space(1))) unsigned int*)(srca + si),
                    (__attribute__((address_space(3))) unsigned int*)(As + s * 256 + w * 64),
                    16, 0, 0);
            }
        }

        // [D] MFMA on registers only
        f32x16 acc[2];
        acc[0] = (f32x16)0.0f;
        acc[1] = (f32x16)0.0f;
        #pragma unroll
        for (int kk = 0; kk < 8; ++kk) {
            U4B a; a.u = af[kk];
            acc[0] = __builtin_amdgcn_mfma_f32_32x32x16_bf16(a.h, Bf[0][kk], acc[0], 0, 0, 0);
            acc[1] = __builtin_amdgcn_mfma_f32_32x32x16_bf16(a.h, Bf[1][kk], acc[1], 0, 0, 0);
        }

        if (i0 < U1 && i0 + 128 > U0) {
            // slow tile: contains same-class rows for some column of the strip
            #pragma unroll
            for (int ct = 0; ct < 2; ++ct) {
                const int tt = tjt[ct];
                #pragma unroll
                for (int r = 0; r < 16; ++r) {
                    float a = acc[ct][r];
                    float v = ur[r] - a;
                    bool same = ((__float_as_int(ur[r]) & 0xff) == tt);
                    Sa[ct] += a;
                    Ss[ct] += same ? a : 0.0f;
                    Mp[ct] = fmaxf(Mp[ct], same ? v : -INFINITY);
                    Mn[ct] = same ? Mn[ct] : fminf(Mn[ct], v);
                }
            }
        } else {
            // fast tile: pure negatives -- 3 VALU ops per element
            #pragma unroll
            for (int ct = 0; ct < 2; ++ct) {
                #pragma unroll
                for (int r = 0; r < 16; ++r) {
                    float a = acc[ct][r];
                    Sa[ct] += a;
                    Mn[ct] = fminf(Mn[ct], ur[r] - a);
                }
            }
        }
        __syncthreads();   // B2: staged tile t+1 landed
    }

    // merge half-lanes, then 4 waves via LDS, write coalesced partial
    #pragma unroll
    for (int ct = 0; ct < 2; ++ct) {
        Sa[ct] += __shfl_xor(Sa[ct], 32, 64);
        Ss[ct] += __shfl_xor(Ss[ct], 32, 64);
        Mp[ct] = fmaxf(Mp[ct], __shfl_xor(Mp[ct], 32, 64));
        Mn[ct] = fminf(Mn[ct], __shfl_xor(Mn[ct], 32, 64));
    }
    if (l < 32) {
        #pragma unroll
        for (int ct = 0; ct < 2; ++ct)
            sm[(ct * 32 + l31) * 4 + w] = make_float4(Sa[ct], Ss[ct], Mp[ct], Mn[ct]);
    }
    __syncthreads();
    if (tid < 64) {
        float4 a = sm[tid * 4 + 0], b = sm[tid * 4 + 1];
        float4 c2 = sm[tid * 4 + 2], d = sm[tid * 4 + 3];
        float4 o;
        o.x = a.x + b.x + c2.x + d.x;
        o.y = a.y + b.y + c2.y + d.y;
        o.z = fmaxf(fmaxf(a.z, b.z), fmaxf(c2.z, d.z));
        o.w = fminf(fminf(a.w, b.w), fminf(c2.w, d.w));
        partial[(size_t)slice * NROWS + col0 + tid] = o;
    }
}

// ---- K3: per-row loss + last-block final reduction ----
__global__ __launch_bounds__(256) void combine_kernel(
        const float* __restrict__ sq, const float* __restrict__ upk,
        const int* __restrict__ hist, const float* __restrict__ S_class,
        const float* __restrict__ bsum, const float4* __restrict__ partial,
        float* __restrict__ blocksum, int* __restrict__ done,
        float* __restrict__ out, int ns) {
    __shared__ float red[4];
    __shared__ float hs[4];
    __shared__ int lastflag;
    int tid = threadIdx.x, l = tid & 63, w = tid >> 6;

    // S_all = sum of prep's 256 per-block sums
    float b = bsum[tid];
    for (int d = 32; d > 0; d >>= 1) b += __shfl_down(b, d, 64);
    if (l == 0) red[w] = b;
    __syncthreads();
    float S_all = red[0] + red[1] + red[2] + red[3];

    int j = blockIdx.x * 256 + tid;
    float Sa = 0.f, Ss = 0.f, Mp = -INFINITY, Mn = INFINITY;
    for (int s = 0; s < ns; ++s) {
        float4 p = partial[(size_t)s * NROWS + j];
        Sa += p.x; Ss += p.y;
        Mp = fmaxf(Mp, p.z); Mn = fminf(Mn, p.w);
    }
    float sqj = sq[j];
    int c = __float_as_int(upk[j]) & 0xff;
    float cnt = (float)hist[c];
    float sumall = (float)NROWS * sqj + S_all - 2.0f * Sa;
    float sump = cnt * sqj + S_class[c] - 2.0f * Ss;
    float sumn = sumall - sump;
    float sigp = sump / (cnt - 1.0f);
    float sign_ = sumn / ((float)NROWS - cnt);
    float ap = (sqj + 2.0f * Mp) / sigp + 0.5f * __logf(sigp);
    float an = (sqj + 2.0f * Mn) / sign_ + 0.5f * __logf(sign_);
    float h = fmaxf(ap - an + MARGIN_F, 0.0f);
    for (int d = 32; d > 0; d >>= 1) h += __shfl_down(h, d, 64);
    if (l == 0) hs[w] = h;
    __syncthreads();
    if (tid == 0) {
        float tot = hs[0] + hs[1] + hs[2] + hs[3];
        __hip_atomic_store(&blocksum[blockIdx.x], tot,
                           __ATOMIC_RELEASE, __HIP_MEMORY_SCOPE_AGENT);
        int prev = __hip_atomic_fetch_add(done, 1,
                                          __ATOMIC_ACQ_REL, __HIP_MEMORY_SCOPE_AGENT);
        lastflag = (prev == 31) ? 1 : 0;
    }
    __syncthreads();
    if (lastflag) {   // order-independent last-block final reduction
        float s2 = 0.0f;
        if (tid < 32)
            s2 = __hip_atomic_load(&blocksum[tid],
                                   __ATOMIC_ACQUIRE, __HIP_MEMORY_SCOPE_AGENT);
        if (tid < 64) {
            for (int d = 32; d > 0; d >>= 1) s2 += __shfl_down(s2, d, 64);
            if (tid == 0) out[0] = s2 * (1.0f / NROWS);
        }
    }
}

extern "C" void kernel_launch(void* const* d_in, const int* in_sizes, int n_in,
                              void* d_out, int out_size, void* d_ws, size_t ws_size,
                              hipStream_t stream) {
    const float* X = (const float*)d_in[0];
    const int* tgt = (const int*)d_in[1];
    float* out = (float*)d_out;

    float* f = (float*)d_ws;
    int*   hist     = (int*)f;                 // [0,256)
    float* S_class  = f + 256;                 // [256,512)
    float* bsum     = f + 512;                 // [512,768)
    float* blocksum = f + 768;                 // [768,800)
    int*   cstart   = (int*)(f + 800);         // [800,1057)
    int*   coffset  = (int*)(f + 1088);        // [1088,1344)
    int*   done     = (int*)(f + 1344);        // [1344,1345)
    float* sq       = f + 2048;                // [2048,10240)
    float* upk      = f + 10240;               // [10240,18432)
    unsigned short* Xbf = (unsigned short*)(f + 18432);  // bf16[1M] -> [18432,542720)
    float4* partial = (float4*)(f + 542720);   // ns*8192 float4

    int ns = 16;
    while (ns > 2 && ws_size < ((size_t)542720 + (size_t)ns * NROWS * 4) * sizeof(float))
        ns >>= 1;
    int shift = (ns == 16) ? 4 : (ns == 8) ? 3 : 2;
    int tiles = 64 / ns;

    histscan_kernel<<<1, 256, 0, stream>>>(tgt, hist, cstart, coffset, S_class, done);
    prep_kernel<<<256, 256, 0, stream>>>(X, tgt, sq, upk, Xbf, coffset, S_class, bsum);
    dist_kernel<<<128 * ns, 256, 0, stream>>>(Xbf, upk, cstart, partial,
                                              ns - 1, shift, tiles);
    combine_kernel<<<32, 256, 0, stream>>>(sq, upk, hist, S_class, bsum,
                                           partial, blocksum, done, out, ns);
}

// Round 3
// 113.746 us; speedup vs baseline: 1.3030x; 1.2133x over previous
//
#include <hip/hip_runtime.h>
#include <math.h>

// TripletLoss round 8: class-sorted rows + double-buffered global_load_lds
// staging + spill-free MFMA loop (fragments read LDS->MFMA directly).
//
// Pipeline: histscan(1 blk) -> prep(scatter by class) -> dist -> combine(+final).
//
// dist K-loop (one barrier per tile, T3 minimum 2-phase):
//   issue stage(t+1) -> As[(t+1)&1]   (async, swizzled-source global_load_lds)
//   ur loads, MFMA+epilogue on As[t&1]  (hides stage latency)
//   __syncthreads()                   (drains vmcnt: tile t+1 landed)
// Swizzle lives in the SOURCE address (rule #21): slot L holds
// src[(L&~15)|((L&15)^((L>>4)&15))], read back with the same XOR on the row.
// ns=8 -> slice==XCD id (bx&7): each XCD's A-slice (1024 rows, 256 KB) stays
// in its own L2. ~96% of tiles are pure-negative: 3-op epilogue.

#define NROWS 8192
#define MARGIN_F 0.3f

typedef short bf16x8 __attribute__((ext_vector_type(8)));
typedef float f32x16 __attribute__((ext_vector_type(16)));
union U4B { uint4 u; bf16x8 h; };

__device__ __forceinline__ unsigned short f2bf(float x) {
    unsigned u = __float_as_uint(x);
    return (unsigned short)((u + 0x7fffu + ((u >> 16) & 1u)) >> 16);
}

// ---- K0: fused histogram + exclusive scan + zero-init (single block) ----
__global__ __launch_bounds__(256) void histscan_kernel(const int* __restrict__ tgt,
                                                       int* __restrict__ hist,
                                                       int* __restrict__ cstart,
                                                       int* __restrict__ coffset,
                                                       float* __restrict__ S_class,
                                                       int* __restrict__ done) {
    __shared__ int h[256];
    __shared__ int wsum[4];
    int t = threadIdx.x;
    h[t] = 0;
    S_class[t] = 0.0f;          // zero for prep's atomics (replaces memset)
    if (t == 0) *done = 0;      // combine's last-block counter
    __syncthreads();
    for (int i = t; i < NROWS; i += 256) atomicAdd(&h[tgt[i]], 1);
    __syncthreads();
    int hv = h[t];
    hist[t] = hv;
    int x = hv;
    #pragma unroll
    for (int d = 1; d < 64; d <<= 1) {
        int y = __shfl_up(x, d, 64);
        if ((t & 63) >= d) x += y;
    }
    if ((t & 63) == 63) wsum[t >> 6] = x;
    __syncthreads();
    int off = 0;
    for (int i = 0; i < (t >> 6); ++i) off += wsum[i];
    int excl = off + x - hv;    // exclusive prefix
    cstart[t] = excl;
    coffset[t] = excl;
    if (t == 255) cstart[256] = NROWS;
}

// ---- K1: bf16 convert + scatter rows into class-sorted order ----
__global__ __launch_bounds__(256) void prep_kernel(const float* __restrict__ X,
                                                   const int* __restrict__ tgt,
                                                   float* __restrict__ sq,
                                                   float* __restrict__ upk,
                                                   unsigned short* __restrict__ Xbf,
                                                   int* __restrict__ coffset,
                                                   float* __restrict__ S_class,
                                                   float* __restrict__ bsum) {
    int tid = threadIdx.x, w = tid >> 6, l = tid & 63;
    int row0 = blockIdx.x * 32 + w * 8;
    float rs = 0.0f;
    #pragma unroll
    for (int i = 0; i < 8; ++i) {
        int r = row0 + i;
        float2 v = ((const float2*)X)[(size_t)r * 64 + l];
        ushort2 h2;
        h2.x = f2bf(v.x);
        h2.y = f2bf(v.y);
        float s = v.x * v.x + v.y * v.y;
        for (int d = 32; d > 0; d >>= 1) s += __shfl_down(s, d, 64);
        int pos = 0;
        if (l == 0) {
            int c = tgt[r];
            pos = atomicAdd(&coffset[c], 1);
            sq[pos] = s;
            rs += s;
            upk[pos] = __uint_as_float((__float_as_uint(0.5f * s) & 0xffffff00u) | (unsigned)c);
            atomicAdd(&S_class[c], s);
        }
        pos = __shfl(pos, 0, 64);
        ((ushort2*)Xbf)[(size_t)pos * 64 + l] = h2;
    }
    __shared__ float bs[4];
    if (l == 0) bs[w] = rs;
    __syncthreads();
    if (tid == 0) bsum[blockIdx.x] = bs[0] + bs[1] + bs[2] + bs[3];
}

// ---- K2: MFMA Gram + fused column stats, dbuf async LDS staging ----
__global__ __launch_bounds__(256, 2) void dist_kernel(
        const unsigned short* __restrict__ Xbf, const float* __restrict__ upk,
        const int* __restrict__ cstart, float4* __restrict__ partial,
        int ns_mask, int jb_shift, int tiles) {
    __shared__ uint4 As[2][2048];      // 2 x 32 KB A tiles (B borrows As[1] once)
    const int tid = threadIdx.x;
    const int w = tid >> 6, l = tid & 63, hl = l >> 5, l31 = l & 31;
    const int bx = blockIdx.x;
    const int slice = bx & ns_mask;   // == XCD id for ns=8
    const int jb = bx >> jb_shift;    // 64-col strip
    const int col0 = jb * 64;

    // ---- prologue: stage B strip (16 KB) -> As[1], tile0 (32 KB) -> As[0] ----
    {
        const uint4* srcb = (const uint4*)Xbf + (size_t)col0 * 16;
        #pragma unroll
        for (int s = 0; s < 4; ++s) {
            int L = s * 256 + tid;
            int si = (L & ~15) | ((L & 15) ^ ((L >> 4) & 15));
            __builtin_amdgcn_global_load_lds(
                (const __attribute__((address_space(1))) unsigned int*)(srcb + si),
                (__attribute__((address_space(3))) unsigned int*)(&As[1][s * 256 + w * 64]),
                16, 0, 0);
        }
    }
    const int row_base = slice * tiles * 128;
    {
        const uint4* srca = (const uint4*)Xbf + (size_t)row_base * 16;
        #pragma unroll
        for (int s = 0; s < 8; ++s) {
            int L = s * 256 + tid;
            int si = (L & ~15) | ((L & 15) ^ ((L >> 4) & 15));
            __builtin_amdgcn_global_load_lds(
                (const __attribute__((address_space(1))) unsigned int*)(srca + si),
                (__attribute__((address_space(3))) unsigned int*)(&As[0][s * 256 + w * 64]),
                16, 0, 0);
        }
    }
    // same-class row window + column tags (regular loads, overlap the stage)
    const int c_first = __float_as_int(upk[col0]) & 0xff;
    const int c_last  = __float_as_int(upk[col0 + 63]) & 0xff;
    const int U0 = cstart[c_first];
    const int U1 = cstart[c_last + 1];
    int tjt[2];
    tjt[0] = __float_as_int(upk[col0 + l31]) & 0xff;
    tjt[1] = __float_as_int(upk[col0 + 32 + l31]) & 0xff;
    __syncthreads();   // B + tile0 landed

    bf16x8 Bf[2][8];
    #pragma unroll
    for (int ct = 0; ct < 2; ++ct) {
        int colb = ct * 32 + l31;
        #pragma unroll
        for (int kk = 0; kk < 8; ++kk) {
            U4B tb; tb.u = As[1][colb * 16 + ((kk * 2 + hl) ^ (colb & 15))];
            Bf[ct][kk] = tb.h;
        }
    }
    __syncthreads();   // Bf reads done block-wide -> As[1] free for tile 1

    float Sa[2] = {0.f, 0.f};
    float Ss[2] = {0.f, 0.f};
    float Mp[2] = {-INFINITY, -INFINITY};
    float Mn[2] = { INFINITY,  INFINITY};
    const int arow = w * 32 + l31;

    for (int t = 0; t < tiles; ++t) {
        const int i0 = row_base + t * 128;

        // [1] issue next tile's async stage first; lands during MFMA+epilogue
        if (t + 1 < tiles) {
            const uint4* srca = (const uint4*)Xbf + (size_t)(i0 + 128) * 16;
            uint4* dst = As[(t + 1) & 1];
            #pragma unroll
            for (int s = 0; s < 8; ++s) {
                int L = s * 256 + tid;
                int si = (L & ~15) | ((L & 15) ^ ((L >> 4) & 15));
                __builtin_amdgcn_global_load_lds(
                    (const __attribute__((address_space(1))) unsigned int*)(srca + si),
                    (__attribute__((address_space(3))) unsigned int*)(dst + s * 256 + w * 64),
                    16, 0, 0);
            }
        }

        // [2] ur loads
        float ur[16];
        const float4* up = (const float4*)(upk + i0 + w * 32 + 4 * hl);
        #pragma unroll
        for (int g = 0; g < 4; ++g) {
            float4 u4 = up[g * 2];
            ur[g * 4 + 0] = u4.x; ur[g * 4 + 1] = u4.y;
            ur[g * 4 + 2] = u4.z; ur[g * 4 + 3] = u4.w;
        }

        // [3] MFMA, A fragments straight from LDS (spill-free, rolling temps)
        const uint4* cur = As[t & 1];
        f32x16 acc[2];
        acc[0] = (f32x16)0.0f;
        acc[1] = (f32x16)0.0f;
        #pragma unroll
        for (int kk = 0; kk < 8; ++kk) {
            U4B a; a.u = cur[arow * 16 + ((kk * 2 + hl) ^ (arow & 15))];
            acc[0] = __builtin_amdgcn_mfma_f32_32x32x16_bf16(a.h, Bf[0][kk], acc[0], 0, 0, 0);
            acc[1] = __builtin_amdgcn_mfma_f32_32x32x16_bf16(a.h, Bf[1][kk], acc[1], 0, 0, 0);
        }

        // [4] epilogue
        if (i0 < U1 && i0 + 128 > U0) {
            // slow tile: contains same-class rows for some column of the strip
            #pragma unroll
            for (int ct = 0; ct < 2; ++ct) {
                const int tt = tjt[ct];
                #pragma unroll
                for (int r = 0; r < 16; ++r) {
                    float a = acc[ct][r];
                    float v = ur[r] - a;
                    bool same = ((__float_as_int(ur[r]) & 0xff) == tt);
                    Sa[ct] += a;
                    Ss[ct] += same ? a : 0.0f;
                    Mp[ct] = fmaxf(Mp[ct], same ? v : -INFINITY);
                    Mn[ct] = same ? Mn[ct] : fminf(Mn[ct], v);
                }
            }
        } else {
            // fast tile: pure negatives -- 3 VALU ops per element
            #pragma unroll
            for (int ct = 0; ct < 2; ++ct) {
                #pragma unroll
                for (int r = 0; r < 16; ++r) {
                    float a = acc[ct][r];
                    Sa[ct] += a;
                    Mn[ct] = fminf(Mn[ct], ur[r] - a);
                }
            }
        }
        __syncthreads();   // stage(t+1) landed; reads of As[t&1] done block-wide
    }

    // merge half-lanes, then 4 waves via LDS (reuse As), write coalesced partial
    #pragma unroll
    for (int ct = 0; ct < 2; ++ct) {
        Sa[ct] += __shfl_xor(Sa[ct], 32, 64);
        Ss[ct] += __shfl_xor(Ss[ct], 32, 64);
        Mp[ct] = fmaxf(Mp[ct], __shfl_xor(Mp[ct], 32, 64));
        Mn[ct] = fminf(Mn[ct], __shfl_xor(Mn[ct], 32, 64));
    }
    float4* sm = (float4*)&As[0][0];   // [64 cols][4 waves]
    if (l < 32) {
        #pragma unroll
        for (int ct = 0; ct < 2; ++ct)
            sm[(ct * 32 + l31) * 4 + w] = make_float4(Sa[ct], Ss[ct], Mp[ct], Mn[ct]);
    }
    __syncthreads();
    if (tid < 64) {
        float4 a = sm[tid * 4 + 0], b = sm[tid * 4 + 1];
        float4 c2 = sm[tid * 4 + 2], d = sm[tid * 4 + 3];
        float4 o;
        o.x = a.x + b.x + c2.x + d.x;
        o.y = a.y + b.y + c2.y + d.y;
        o.z = fmaxf(fmaxf(a.z, b.z), fmaxf(c2.z, d.z));
        o.w = fminf(fminf(a.w, b.w), fminf(c2.w, d.w));
        partial[(size_t)slice * NROWS + col0 + tid] = o;
    }
}

// ---- K3: per-row loss + last-block final reduction ----
__global__ __launch_bounds__(256) void combine_kernel(
        const float* __restrict__ sq, const float* __restrict__ upk,
        const int* __restrict__ hist, const float* __restrict__ S_class,
        const float* __restrict__ bsum, const float4* __restrict__ partial,
        float* __restrict__ blocksum, int* __restrict__ done,
        float* __restrict__ out, int ns) {
    __shared__ float red[4];
    __shared__ float hs[4];
    __shared__ int lastflag;
    int tid = threadIdx.x, l = tid & 63, w = tid >> 6;

    // S_all = sum of prep's 256 per-block sums
    float b = bsum[tid];
    for (int d = 32; d > 0; d >>= 1) b += __shfl_down(b, d, 64);
    if (l == 0) red[w] = b;
    __syncthreads();
    float S_all = red[0] + red[1] + red[2] + red[3];

    int j = blockIdx.x * 256 + tid;
    float Sa = 0.f, Ss = 0.f, Mp = -INFINITY, Mn = INFINITY;
    for (int s = 0; s < ns; ++s) {
        float4 p = partial[(size_t)s * NROWS + j];
        Sa += p.x; Ss += p.y;
        Mp = fmaxf(Mp, p.z); Mn = fminf(Mn, p.w);
    }
    float sqj = sq[j];
    int c = __float_as_int(upk[j]) & 0xff;
    float cnt = (float)hist[c];
    float sumall = (float)NROWS * sqj + S_all - 2.0f * Sa;
    float sump = cnt * sqj + S_class[c] - 2.0f * Ss;
    float sumn = sumall - sump;
    float sigp = sump / (cnt - 1.0f);
    float sign_ = sumn / ((float)NROWS - cnt);
    float ap = (sqj + 2.0f * Mp) / sigp + 0.5f * __logf(sigp);
    float an = (sqj + 2.0f * Mn) / sign_ + 0.5f * __logf(sign_);
    float h = fmaxf(ap - an + MARGIN_F, 0.0f);
    for (int d = 32; d > 0; d >>= 1) h += __shfl_down(h, d, 64);
    if (l == 0) hs[w] = h;
    __syncthreads();
    if (tid == 0) {
        float tot = hs[0] + hs[1] + hs[2] + hs[3];
        __hip_atomic_store(&blocksum[blockIdx.x], tot,
                           __ATOMIC_RELEASE, __HIP_MEMORY_SCOPE_AGENT);
        int prev = __hip_atomic_fetch_add(done, 1,
                                          __ATOMIC_ACQ_REL, __HIP_MEMORY_SCOPE_AGENT);
        lastflag = (prev == 31) ? 1 : 0;
    }
    __syncthreads();
    if (lastflag) {   // order-independent last-block final reduction
        float s2 = 0.0f;
        if (tid < 32)
            s2 = __hip_atomic_load(&blocksum[tid],
                                   __ATOMIC_ACQUIRE, __HIP_MEMORY_SCOPE_AGENT);
        if (tid < 64) {
            for (int d = 32; d > 0; d >>= 1) s2 += __shfl_down(s2, d, 64);
            if (tid == 0) out[0] = s2 * (1.0f / NROWS);
        }
    }
}

extern "C" void kernel_launch(void* const* d_in, const int* in_sizes, int n_in,
                              void* d_out, int out_size, void* d_ws, size_t ws_size,
                              hipStream_t stream) {
    const float* X = (const float*)d_in[0];
    const int* tgt = (const int*)d_in[1];
    float* out = (float*)d_out;

    float* f = (float*)d_ws;
    int*   hist     = (int*)f;                 // [0,256)
    float* S_class  = f + 256;                 // [256,512)
    float* bsum     = f + 512;                 // [512,768)
    float* blocksum = f + 768;                 // [768,800)
    int*   cstart   = (int*)(f + 800);         // [800,1057)
    int*   coffset  = (int*)(f + 1088);        // [1088,1344)
    int*   done     = (int*)(f + 1344);        // [1344,1345)
    float* sq       = f + 2048;                // [2048,10240)
    float* upk      = f + 10240;               // [10240,18432)
    unsigned short* Xbf = (unsigned short*)(f + 18432);  // bf16[1M] -> [18432,542720)
    float4* partial = (float4*)(f + 542720);   // ns*8192 float4

    int ns = 8;   // slice == XCD id; 8 tiles/block pipeline depth
    while (ns > 2 && ws_size < ((size_t)542720 + (size_t)ns * NROWS * 4) * sizeof(float))
        ns >>= 1;
    int shift = (ns == 8) ? 3 : (ns == 4) ? 2 : 1;
    int tiles = 64 / ns;

    histscan_kernel<<<1, 256, 0, stream>>>(tgt, hist, cstart, coffset, S_class, done);
    prep_kernel<<<256, 256, 0, stream>>>(X, tgt, sq, upk, Xbf, coffset, S_class, bsum);
    dist_kernel<<<128 * ns, 256, 0, stream>>>(Xbf, upk, cstart, partial,
                                              ns - 1, shift, tiles);
    combine_kernel<<<32, 256, 0, stream>>>(sq, upk, hist, S_class, bsum,
                                           partial, blocksum, done, out, ns);
}

// Round 4
// 106.997 us; speedup vs baseline: 1.3852x; 1.0631x over previous
//
#include <hip/hip_runtime.h>
#include <math.h>

// TripletLoss round 9: fragment-major Xbf layout -> barrier-free, LDS-free dist.
//
// Pipeline: histscan(1 blk) -> prep(scatter by class, chunk layout) -> dist
//           -> combine(+final).
//
// Xbf layout (chunk-major): chunk (g,c) = rows g*32..g*32+31, k-cols c*8..c*8+7,
// stored as 32 x 16B contiguous: uint4 index (g*16+c)*32 + r. A wave's MFMA
// A/B-fragment load (32 lanes x 16B, two k-chunks per wave) is then one fully
// coalesced 1 KB global_load_dwordx4 -> no LDS staging, no K-loop barriers,
// waves free-run; A-slice (256 KB) stays XCD-L2-resident (slice == bx&7 == XCD).
// Class-sorted rows: ~96% of tiles pure-negative -> 3-op epilogue.

#define NROWS 8192
#define MARGIN_F 0.3f

typedef short bf16x8 __attribute__((ext_vector_type(8)));
typedef float f32x16 __attribute__((ext_vector_type(16)));
union U4B { uint4 u; bf16x8 h; };

__device__ __forceinline__ unsigned short f2bf(float x) {
    unsigned u = __float_as_uint(x);
    return (unsigned short)((u + 0x7fffu + ((u >> 16) & 1u)) >> 16);
}

// ---- K0: fused histogram + exclusive scan + zero-init (single block) ----
__global__ __launch_bounds__(256) void histscan_kernel(const int* __restrict__ tgt,
                                                       int* __restrict__ hist,
                                                       int* __restrict__ cstart,
                                                       int* __restrict__ coffset,
                                                       float* __restrict__ S_class,
                                                       int* __restrict__ done) {
    __shared__ int h[256];
    __shared__ int wsum[4];
    int t = threadIdx.x;
    h[t] = 0;
    S_class[t] = 0.0f;          // zero for prep's atomics (replaces memset)
    if (t == 0) *done = 0;      // combine's last-block counter
    __syncthreads();
    const int4* t4 = (const int4*)tgt;
    for (int i = t; i < NROWS / 4; i += 256) {
        int4 v = t4[i];
        atomicAdd(&h[v.x], 1);
        atomicAdd(&h[v.y], 1);
        atomicAdd(&h[v.z], 1);
        atomicAdd(&h[v.w], 1);
    }
    __syncthreads();
    int hv = h[t];
    hist[t] = hv;
    int x = hv;
    #pragma unroll
    for (int d = 1; d < 64; d <<= 1) {
        int y = __shfl_up(x, d, 64);
        if ((t & 63) >= d) x += y;
    }
    if ((t & 63) == 63) wsum[t >> 6] = x;
    __syncthreads();
    int off = 0;
    for (int i = 0; i < (t >> 6); ++i) off += wsum[i];
    int excl = off + x - hv;    // exclusive prefix
    cstart[t] = excl;
    coffset[t] = excl;
    if (t == 255) cstart[256] = NROWS;
}

// ---- K1: bf16 convert + scatter rows into class-sorted chunk layout ----
__global__ __launch_bounds__(256) void prep_kernel(const float* __restrict__ X,
                                                   const int* __restrict__ tgt,
                                                   float* __restrict__ sq,
                                                   float* __restrict__ upk,
                                                   unsigned short* __restrict__ Xbf,
                                                   int* __restrict__ coffset,
                                                   float* __restrict__ S_class,
                                                   float* __restrict__ bsum) {
    int tid = threadIdx.x, w = tid >> 6, l = tid & 63;
    int row0 = blockIdx.x * 32 + w * 8;
    float rs = 0.0f;
    #pragma unroll
    for (int i = 0; i < 8; ++i) {
        int r = row0 + i;
        float2 v = ((const float2*)X)[(size_t)r * 64 + l];
        ushort2 h2;
        h2.x = f2bf(v.x);
        h2.y = f2bf(v.y);
        float s = v.x * v.x + v.y * v.y;
        for (int d = 32; d > 0; d >>= 1) s += __shfl_down(s, d, 64);
        int pos = 0;
        if (l == 0) {
            int c = tgt[r];
            pos = atomicAdd(&coffset[c], 1);
            sq[pos] = s;
            rs += s;
            upk[pos] = __uint_as_float((__float_as_uint(0.5f * s) & 0xffffff00u) | (unsigned)c);
            atomicAdd(&S_class[c], s);
        }
        pos = __shfl(pos, 0, 64);
        // chunk-major: row pos -> (g = pos>>5, rr = pos&31); lane l holds cols
        // 2l..2l+1 -> chunk c = l>>2, slot l&3.  ushort2 index:
        int g = pos >> 5, rr = pos & 31;
        ((ushort2*)Xbf)[((size_t)(g * 16 + (l >> 2)) * 32 + rr) * 4 + (l & 3)] = h2;
    }
    __shared__ float bs[4];
    if (l == 0) bs[w] = rs;
    __syncthreads();
    if (tid == 0) bsum[blockIdx.x] = bs[0] + bs[1] + bs[2] + bs[3];
}

// ---- K2: MFMA Gram + fused column stats, barrier-free streaming ----
__global__ __launch_bounds__(256, 2) void dist_kernel(
        const unsigned short* __restrict__ Xbf, const float* __restrict__ upk,
        const int* __restrict__ cstart, float4* __restrict__ partial,
        int ns_mask, int jb_shift, int tiles) {
    __shared__ float4 sm[64 * 4];
    const int tid = threadIdx.x;
    const int w = tid >> 6, l = tid & 63, hl = l >> 5, l31 = l & 31;
    const int bx = blockIdx.x;
    const int slice = bx & ns_mask;   // == XCD id for ns=8
    const int jb = bx >> jb_shift;    // 64-col strip
    const int col0 = jb * 64;
    const uint4* Xq = (const uint4*)Xbf;

    // B fragments straight from global (chunk layout: 1 KB coalesced per read)
    bf16x8 Bf[2][8];
    #pragma unroll
    for (int ct = 0; ct < 2; ++ct) {
        const uint4* bp = Xq + (size_t)(jb * 2 + ct) * 512 + hl * 32 + l31;
        #pragma unroll
        for (int kk = 0; kk < 8; ++kk) {
            U4B tb; tb.u = bp[kk * 64];
            Bf[ct][kk] = tb.h;
        }
    }
    int tjt[2];
    tjt[0] = __float_as_int(upk[col0 + l31]) & 0xff;
    tjt[1] = __float_as_int(upk[col0 + 32 + l31]) & 0xff;
    // same-class row window for the whole strip (classes ascending with row)
    const int c_first = __float_as_int(upk[col0]) & 0xff;
    const int c_last  = __float_as_int(upk[col0 + 63]) & 0xff;
    const int U0 = cstart[c_first];
    const int U1 = cstart[c_last + 1];

    float Sa[2] = {0.f, 0.f};
    float Ss[2] = {0.f, 0.f};
    float Mp[2] = {-INFINITY, -INFINITY};
    float Mn[2] = { INFINITY,  INFINITY};
    const int row_base = slice * tiles * 128;

    for (int t = 0; t < tiles; ++t) {
        const int i0 = row_base + t * 128;

        // ur loads (row-major f32, coalesced)
        float ur[16];
        const float4* up = (const float4*)(upk + i0 + w * 32 + 4 * hl);
        #pragma unroll
        for (int g = 0; g < 4; ++g) {
            float4 u4 = up[g * 2];
            ur[g * 4 + 0] = u4.x; ur[g * 4 + 1] = u4.y;
            ur[g * 4 + 2] = u4.z; ur[g * 4 + 3] = u4.w;
        }

        // MFMA: A fragments straight from global (rolling temps, spill-free)
        const uint4* ap = Xq + ((size_t)(i0 >> 5) + w) * 512 + hl * 32 + l31;
        f32x16 acc[2];
        acc[0] = (f32x16)0.0f;
        acc[1] = (f32x16)0.0f;
        #pragma unroll
        for (int kk = 0; kk < 8; ++kk) {
            U4B a; a.u = ap[kk * 64];
            acc[0] = __builtin_amdgcn_mfma_f32_32x32x16_bf16(a.h, Bf[0][kk], acc[0], 0, 0, 0);
            acc[1] = __builtin_amdgcn_mfma_f32_32x32x16_bf16(a.h, Bf[1][kk], acc[1], 0, 0, 0);
        }

        if (i0 < U1 && i0 + 128 > U0) {
            // slow tile: contains same-class rows for some column of the strip
            #pragma unroll
            for (int ct = 0; ct < 2; ++ct) {
                const int tt = tjt[ct];
                #pragma unroll
                for (int r = 0; r < 16; ++r) {
                    float a = acc[ct][r];
                    float v = ur[r] - a;
                    bool same = ((__float_as_int(ur[r]) & 0xff) == tt);
                    Sa[ct] += a;
                    Ss[ct] += same ? a : 0.0f;
                    Mp[ct] = fmaxf(Mp[ct], same ? v : -INFINITY);
                    Mn[ct] = same ? Mn[ct] : fminf(Mn[ct], v);
                }
            }
        } else {
            // fast tile: pure negatives -- 3 VALU ops per element
            #pragma unroll
            for (int ct = 0; ct < 2; ++ct) {
                #pragma unroll
                for (int r = 0; r < 16; ++r) {
                    float a = acc[ct][r];
                    Sa[ct] += a;
                    Mn[ct] = fminf(Mn[ct], ur[r] - a);
                }
            }
        }
    }

    // merge half-lanes, then 4 waves via LDS, write coalesced partial
    #pragma unroll
    for (int ct = 0; ct < 2; ++ct) {
        Sa[ct] += __shfl_xor(Sa[ct], 32, 64);
        Ss[ct] += __shfl_xor(Ss[ct], 32, 64);
        Mp[ct] = fmaxf(Mp[ct], __shfl_xor(Mp[ct], 32, 64));
        Mn[ct] = fminf(Mn[ct], __shfl_xor(Mn[ct], 32, 64));
    }
    if (l < 32) {
        #pragma unroll
        for (int ct = 0; ct < 2; ++ct)
            sm[(ct * 32 + l31) * 4 + w] = make_float4(Sa[ct], Ss[ct], Mp[ct], Mn[ct]);
    }
    __syncthreads();
    if (tid < 64) {
        float4 a = sm[tid * 4 + 0], b = sm[tid * 4 + 1];
        float4 c2 = sm[tid * 4 + 2], d = sm[tid * 4 + 3];
        float4 o;
        o.x = a.x + b.x + c2.x + d.x;
        o.y = a.y + b.y + c2.y + d.y;
        o.z = fmaxf(fmaxf(a.z, b.z), fmaxf(c2.z, d.z));
        o.w = fminf(fminf(a.w, b.w), fminf(c2.w, d.w));
        partial[(size_t)slice * NROWS + col0 + tid] = o;
    }
}

// ---- K3: per-row loss + last-block final reduction ----
__global__ __launch_bounds__(256) void combine_kernel(
        const float* __restrict__ sq, const float* __restrict__ upk,
        const int* __restrict__ hist, const float* __restrict__ S_class,
        const float* __restrict__ bsum, const float4* __restrict__ partial,
        float* __restrict__ blocksum, int* __restrict__ done,
        float* __restrict__ out, int ns) {
    __shared__ float red[4];
    __shared__ float hs[4];
    __shared__ int lastflag;
    int tid = threadIdx.x, l = tid & 63, w = tid >> 6;

    // S_all = sum of prep's 256 per-block sums
    float b = bsum[tid];
    for (int d = 32; d > 0; d >>= 1) b += __shfl_down(b, d, 64);
    if (l == 0) red[w] = b;
    __syncthreads();
    float S_all = red[0] + red[1] + red[2] + red[3];

    int j = blockIdx.x * 256 + tid;
    float Sa = 0.f, Ss = 0.f, Mp = -INFINITY, Mn = INFINITY;
    for (int s = 0; s < ns; ++s) {
        float4 p = partial[(size_t)s * NROWS + j];
        Sa += p.x; Ss += p.y;
        Mp = fmaxf(Mp, p.z); Mn = fminf(Mn, p.w);
    }
    float sqj = sq[j];
    int c = __float_as_int(upk[j]) & 0xff;
    float cnt = (float)hist[c];
    float sumall = (float)NROWS * sqj + S_all - 2.0f * Sa;
    float sump = cnt * sqj + S_class[c] - 2.0f * Ss;
    float sumn = sumall - sump;
    float sigp = sump / (cnt - 1.0f);
    float sign_ = sumn / ((float)NROWS - cnt);
    float ap = (sqj + 2.0f * Mp) / sigp + 0.5f * __logf(sigp);
    float an = (sqj + 2.0f * Mn) / sign_ + 0.5f * __logf(sign_);
    float h = fmaxf(ap - an + MARGIN_F, 0.0f);
    for (int d = 32; d > 0; d >>= 1) h += __shfl_down(h, d, 64);
    if (l == 0) hs[w] = h;
    __syncthreads();
    if (tid == 0) {
        float tot = hs[0] + hs[1] + hs[2] + hs[3];
        __hip_atomic_store(&blocksum[blockIdx.x], tot,
                           __ATOMIC_RELEASE, __HIP_MEMORY_SCOPE_AGENT);
        int prev = __hip_atomic_fetch_add(done, 1,
                                          __ATOMIC_ACQ_REL, __HIP_MEMORY_SCOPE_AGENT);
        lastflag = (prev == 31) ? 1 : 0;
    }
    __syncthreads();
    if (lastflag) {   // order-independent last-block final reduction
        float s2 = 0.0f;
        if (tid < 32)
            s2 = __hip_atomic_load(&blocksum[tid],
                                   __ATOMIC_ACQUIRE, __HIP_MEMORY_SCOPE_AGENT);
        if (tid < 64) {
            for (int d = 32; d > 0; d >>= 1) s2 += __shfl_down(s2, d, 64);
            if (tid == 0) out[0] = s2 * (1.0f / NROWS);
        }
    }
}

extern "C" void kernel_launch(void* const* d_in, const int* in_sizes, int n_in,
                              void* d_out, int out_size, void* d_ws, size_t ws_size,
                              hipStream_t stream) {
    const float* X = (const float*)d_in[0];
    const int* tgt = (const int*)d_in[1];
    float* out = (float*)d_out;

    float* f = (float*)d_ws;
    int*   hist     = (int*)f;                 // [0,256)
    float* S_class  = f + 256;                 // [256,512)
    float* bsum     = f + 512;                 // [512,768)
    float* blocksum = f + 768;                 // [768,800)
    int*   cstart   = (int*)(f + 800);         // [800,1057)
    int*   coffset  = (int*)(f + 1088);        // [1088,1344)
    int*   done     = (int*)(f + 1344);        // [1344,1345)
    float* sq       = f + 2048;                // [2048,10240)
    float* upk      = f + 10240;               // [10240,18432)
    unsigned short* Xbf = (unsigned short*)(f + 18432);  // bf16[1M] -> [18432,542720)
    float4* partial = (float4*)(f + 542720);   // ns*8192 float4

    int ns = 8;   // slice == XCD id
    while (ns > 2 && ws_size < ((size_t)542720 + (size_t)ns * NROWS * 4) * sizeof(float))
        ns >>= 1;
    int shift = (ns == 8) ? 3 : (ns == 4) ? 2 : 1;
    int tiles = 64 / ns;

    histscan_kernel<<<1, 256, 0, stream>>>(tgt, hist, cstart, coffset, S_class, done);
    prep_kernel<<<256, 256, 0, stream>>>(X, tgt, sq, upk, Xbf, coffset, S_class, bsum);
    dist_kernel<<<128 * ns, 256, 0, stream>>>(Xbf, upk, cstart, partial,
                                              ns - 1, shift, tiles);
    combine_kernel<<<32, 256, 0, stream>>>(sq, upk, hist, S_class, bsum,
                                           partial, blocksum, done, out, ns);
}